// Round 4
// baseline (609.333 us; speedup 1.0000x reference)
//
#include <hip/hip_runtime.h>

// CrossAttention: B=4, L=256, D=2048, LE=2048, DE=1024, H=16, HD=128
// R4: register-direct barrier-free K-loop (AITER-style vmcnt pipelining):
//     each wave loads its own MFMA fragments via global_load_dwordx4 with an
//     explicit one-chunk-ahead register double buffer; NO LDS / no barrier in
//     the K-loop (LDS only for the epilogue bounce). Applied to all 5 GEMMs.

#define B_ 4
#define L_ 256
#define D_ 2048
#define LE_ 2048
#define DE_ 1024
#define H_ 16
#define HD_ 128

using f32x4  = __attribute__((ext_vector_type(4))) float;
using bf16x8 = __attribute__((ext_vector_type(8))) short;

__device__ __forceinline__ unsigned short f2bf(float f) {
    union { float f; unsigned int u; } v; v.f = f;
    unsigned int r = v.u + 0x7fffu + ((v.u >> 16) & 1u);   // RNE
    return (unsigned short)(r >> 16);
}
__device__ __forceinline__ float b2f(unsigned short h) {
    union { unsigned int u; float f; } v; v.u = ((unsigned int)h) << 16;
    return v.f;
}

// ---------------- elementwise cast fp32 -> bf16 (vec4) ----------------
__global__ void cast_f32_bf16(const float* __restrict__ in, unsigned short* __restrict__ out, int n) {
    int i = (blockIdx.x * 256 + threadIdx.x) * 4;
    if (i < n) {
        float4 v = *(const float4*)(in + i);
        ushort4 o;
        o.x = f2bf(v.x); o.y = f2bf(v.y); o.z = f2bf(v.z); o.w = f2bf(v.w);
        *(ushort4*)(out + i) = o;
    }
}

// ---------------- tiled transpose fp32[R,C] -> bf16[C,R] ----------------
__global__ void transpose_f32_bf16(const float* __restrict__ in, unsigned short* __restrict__ out,
                                   int R, int C) {
    __shared__ float t[32][33];
    int r0 = blockIdx.y * 32, c0 = blockIdx.x * 32;
    int tx = threadIdx.x, ty = threadIdx.y;            // block (32,8)
    #pragma unroll
    for (int i = 0; i < 32; i += 8) t[ty + i][tx] = in[(long)(r0 + ty + i) * C + c0 + tx];
    __syncthreads();
    #pragma unroll
    for (int i = 0; i < 32; i += 8) out[(long)(c0 + ty + i) * R + r0 + tx] = f2bf(t[tx][ty + i]);
}

// ---------------- tiled transpose bf16[R,C] -> bf16[C,R], batched (z) ----------------
__global__ void transpose_bf16_batched(const unsigned short* __restrict__ in,
                                       unsigned short* __restrict__ out, int R, int C) {
    __shared__ unsigned short t[32][33];
    long zo = (long)blockIdx.z * R * C;
    int r0 = blockIdx.y * 32, c0 = blockIdx.x * 32;
    int tx = threadIdx.x, ty = threadIdx.y;            // block (32,8)
    #pragma unroll
    for (int i = 0; i < 32; i += 8) t[ty + i][tx] = in[zo + (long)(r0 + ty + i) * C + c0 + tx];
    __syncthreads();
    #pragma unroll
    for (int i = 0; i < 32; i += 8) out[zo + (long)(c0 + ty + i) * R + r0 + tx] = t[tx][ty + i];
}

// ---------------- combine Q split-K partials + bias + RoPE -> Q_bf head layout ----------------
__global__ void combine_q_rope(const float* __restrict__ P, const float* __restrict__ bq,
                               unsigned short* __restrict__ Q) {
    int gid = blockIdx.x * 256 + threadIdx.x;          // 1,048,576 pairs
    int p = gid & 63;
    int h = (gid >> 6) & 15;
    int m = gid >> 10;                                 // 0..1023
    int n = h * 128 + 2 * p;
    long i0 = (long)m * 2048 + n;
    float2 a  = *(const float2*)(P + i0);
    float2 b2 = *(const float2*)(P + 2097152 + i0);
    float q1 = a.x + b2.x + bq[n];
    float q2 = a.y + b2.y + bq[n + 1];
    int l = m & 255, b = m >> 8;
    float inv = powf(10000.0f, -(float)p * (1.0f / 64.0f));
    float s, c;
    sincosf((float)l * inv, &s, &c);
    const float sc = 0.08838834764831845f;             // 1/sqrt(128)
    long qi = (((long)(b * 16 + h) * 256 + l) << 7) + 2 * p;
    ushort2 o;
    o.x = f2bf((q1 * c - q2 * s) * sc);
    o.y = f2bf((q1 * s + q2 * c) * sc);
    *(ushort2*)(Q + qi) = o;
}

// ---------------- combine PV split-K partials -> ctx_bf ----------------
__global__ void combine_pv(const float* __restrict__ P, unsigned short* __restrict__ ctx) {
    int gid = blockIdx.x * 256 + threadIdx.x;          // 524288 threads, 4 floats each
    long e = (long)gid * 4;
    float4 a = *(const float4*)(P + e);
    float4 b = *(const float4*)(P + 2097152 + e);
    int bh = (int)(e >> 15);
    int m  = (int)((e >> 7) & 255);
    int d  = (int)(e & 127);
    int bb = bh >> 4, h = bh & 15;
    ushort4 o;
    o.x = f2bf(a.x + b.x); o.y = f2bf(a.y + b.y);
    o.z = f2bf(a.z + b.z); o.w = f2bf(a.w + b.w);
    *(ushort4*)(ctx + ((long)(bb * 256 + m)) * 2048 + h * 128 + d) = o;
}

// ---------------- combine O split-K partials + bias -> fp32 out ----------------
__global__ void combine_o(const float* __restrict__ P, const float* __restrict__ bo,
                          float* __restrict__ out) {
    int gid = blockIdx.x * 256 + threadIdx.x;          // 524288
    long e = (long)gid * 4;
    float4 a = *(const float4*)(P + e);
    float4 b = *(const float4*)(P + 2097152 + e);
    int n = (int)(e & 2047);
    float4 bb = *(const float4*)(bo + n);
    float4 r;
    r.x = a.x + b.x + bb.x; r.y = a.y + b.y + bb.y;
    r.z = a.z + b.z + bb.z; r.w = a.w + b.w + bb.w;
    *(float4*)(out + e) = r;
}

// ---------------- row softmax, in-place on bf16 rows of 2048 (16B/thread) ----------------
__launch_bounds__(256)
__global__ void softmax_rows(unsigned short* __restrict__ S) {
    long row = blockIdx.x;
    unsigned short* p = S + row * 2048;
    int t = threadIdx.x, w = t >> 6, lane = t & 63;
    bf16x8 raw = *(const bf16x8*)(p + t * 8);
    float v[8];
    float mx = -1e30f;
    #pragma unroll
    for (int i = 0; i < 8; i++) { v[i] = b2f((unsigned short)raw[i]); mx = fmaxf(mx, v[i]); }
    #pragma unroll
    for (int o = 32; o; o >>= 1) mx = fmaxf(mx, __shfl_xor(mx, o));
    __shared__ float redm[4], reds[4];
    if (lane == 0) redm[w] = mx;
    __syncthreads();
    mx = fmaxf(fmaxf(redm[0], redm[1]), fmaxf(redm[2], redm[3]));
    float sum = 0.f;
    #pragma unroll
    for (int i = 0; i < 8; i++) { v[i] = __expf(v[i] - mx); sum += v[i]; }
    #pragma unroll
    for (int o = 32; o; o >>= 1) sum += __shfl_xor(sum, o);
    if (lane == 0) reds[w] = sum;
    __syncthreads();
    sum = reds[0] + reds[1] + reds[2] + reds[3];
    float r = 1.0f / sum;
    bf16x8 res;
    #pragma unroll
    for (int i = 0; i < 8; i++) res[i] = (short)f2bf(v[i] * r);
    *(bf16x8*)(p + t * 8) = res;
}

// ---------------- bf16 GEMM, register-direct barrier-free K-loop ----------------
// C[M,N] = A[M,K] * Bt[N,K]^T. No LDS staging: each wave loads its own
// fragments (global_load_dwordx4, 16B contiguous in k) with a one-chunk-ahead
// register double buffer -> compiler emits partial vmcnt waits, loads stay in
// flight across MFMA blocks. LDS used only for the vectorized epilogue.
// EPI 1: bf16 KV head relayout; n<nsplit -> outA(K_bf)+biasA, else outB(V_bf)+biasB
// EPI 2: bf16 plain batched [z][M,N]
// EPI 4: fp32 split-K partial; z -> s=z/zdiv, bh=z%zdiv; out[(s*zdiv+bh)][M][N]
template <int EPI>
__launch_bounds__(256)
__global__ void gemm_bt(const unsigned short* __restrict__ A, const unsigned short* __restrict__ Bt,
                        const float* __restrict__ biasA, const float* __restrict__ biasB,
                        void* __restrict__ outA, void* __restrict__ outB,
                        int M, int N, int K, int lda, int ldb,
                        long strideA, long strideB, int zdiv, int nsplit) {
    __shared__ __align__(16) unsigned short smem[8704];   // epilogue bounce only (17408 B)
    const int z = blockIdx.z;
    int s = 0, bh = z;
    if constexpr (EPI == 4) { s = z / zdiv; bh = z - s * zdiv; }
    const unsigned short* Ab = A + (long)bh * strideA + (long)s * K;
    const unsigned short* Bb = Bt + (long)bh * strideB + (long)s * K;
    const int m0 = blockIdx.y * 128, n0 = blockIdx.x * 128;
    const int tid = threadIdx.x;
    const int w = tid >> 6, lane = tid & 63;
    const int quad = lane >> 4, l16 = lane & 15;
    const int wr = w >> 1, wc = w & 1;

    // per-fragment row base pointers (lane-resident): frag element = 16B at k-offset
    const unsigned short* Arow[4];
    const unsigned short* Brow[4];
    #pragma unroll
    for (int i = 0; i < 4; i++)
        Arow[i] = Ab + (long)(m0 + wr * 64 + i * 16 + l16) * lda + quad * 8;
    #pragma unroll
    for (int j = 0; j < 4; j++)
        Brow[j] = Bb + (long)(n0 + wc * 64 + j * 16 + l16) * ldb + quad * 8;

    f32x4 acc[4][4] = {};
    bf16x8 a0[4], b0[4], a1[4], b1[4];

    #pragma unroll
    for (int i = 0; i < 4; i++) a0[i] = *(const bf16x8*)(Arow[i]);
    #pragma unroll
    for (int j = 0; j < 4; j++) b0[j] = *(const bf16x8*)(Brow[j]);

    // K is always a multiple of 64 here (128 / 1024 / 2048)
    for (int k = 0; k + 64 <= K; k += 64) {
        #pragma unroll
        for (int i = 0; i < 4; i++) a1[i] = *(const bf16x8*)(Arow[i] + k + 32);
        #pragma unroll
        for (int j = 0; j < 4; j++) b1[j] = *(const bf16x8*)(Brow[j] + k + 32);
        #pragma unroll
        for (int i = 0; i < 4; i++)
            #pragma unroll
            for (int j = 0; j < 4; j++)
                acc[i][j] = __builtin_amdgcn_mfma_f32_16x16x32_bf16(a0[i], b0[j], acc[i][j], 0, 0, 0);
        if (k + 64 < K) {
            #pragma unroll
            for (int i = 0; i < 4; i++) a0[i] = *(const bf16x8*)(Arow[i] + k + 64);
            #pragma unroll
            for (int j = 0; j < 4; j++) b0[j] = *(const bf16x8*)(Brow[j] + k + 64);
        }
        #pragma unroll
        for (int i = 0; i < 4; i++)
            #pragma unroll
            for (int j = 0; j < 4; j++)
                acc[i][j] = __builtin_amdgcn_mfma_f32_16x16x32_bf16(a1[i], b1[j], acc[i][j], 0, 0, 0);
    }

    // ---------------- epilogue via LDS bounce ----------------
    if constexpr (EPI == 1 || EPI == 2) {
        const bool second = (EPI == 1) && (n0 >= nsplit);
        const float* bias = second ? biasB : biasA;
        const int n0e = second ? n0 - nsplit : n0;
        unsigned short* dst = (unsigned short*)(second ? outB : outA);
        #pragma unroll
        for (int p = 0; p < 2; p++) {
            if (wr == p) {
                #pragma unroll
                for (int i = 0; i < 4; i++)
                    #pragma unroll
                    for (int j = 0; j < 4; j++)
                        #pragma unroll
                        for (int r = 0; r < 4; r++) {
                            int ml = i * 16 + quad * 4 + r;          // 0..63
                            int n  = wc * 64 + j * 16 + l16;         // 0..127
                            float v = acc[i][j][r];
                            if (bias) v += bias[n0e + n];
                            smem[ml * 136 + n] = f2bf(v);
                        }
            }
            __syncthreads();
            #pragma unroll
            for (int pass = 0; pass < 4; pass++) {
                int row = pass * 16 + (tid >> 4);                    // 0..63
                int seg = tid & 15;                                  // x8 elems
                bf16x8 val = *(const bf16x8*)(smem + row * 136 + seg * 8);
                int m = m0 + p * 64 + row;
                if constexpr (EPI == 1) {
                    int h = n0e >> 7;                                // 0..15
                    int b = m >> 11, mrow = m & 2047;
                    long idx = (((long)(b * 16 + h)) << 11) + mrow;
                    *(bf16x8*)(dst + (idx << 7) + seg * 8) = val;
                } else {
                    *(bf16x8*)((unsigned short*)outA + (long)z * M * N + (long)m * N + n0 + seg * 8) = val;
                }
            }
            __syncthreads();
        }
    } else {
        // fp32 split-K partial
        float* smf = (float*)smem;
        long zo = ((long)s * zdiv + bh) * (long)M * N;
        #pragma unroll
        for (int q4 = 0; q4 < 4; q4++) {
            if (wr == (q4 >> 1)) {
                #pragma unroll
                for (int ii = 0; ii < 2; ii++) {
                    int i = (q4 & 1) * 2 + ii;
                    #pragma unroll
                    for (int j = 0; j < 4; j++)
                        #pragma unroll
                        for (int r = 0; r < 4; r++) {
                            int ml = ii * 16 + quad * 4 + r;         // 0..31
                            int n  = wc * 64 + j * 16 + l16;
                            smf[ml * 132 + n] = acc[i][j][r];
                        }
                }
            }
            __syncthreads();
            #pragma unroll
            for (int pass = 0; pass < 4; pass++) {
                int row = pass * 8 + (tid >> 5);                     // 0..31
                int seg = tid & 31;                                  // x4 floats
                float4 val = *(const float4*)(smf + row * 132 + seg * 4);
                int m = m0 + q4 * 32 + row;
                *(float4*)((float*)outA + zo + (long)m * N + n0 + seg * 4) = val;
            }
            __syncthreads();
        }
    }
}

extern "C" void kernel_launch(void* const* d_in, const int* in_sizes, int n_in,
                              void* d_out, int out_size, void* d_ws, size_t ws_size,
                              hipStream_t stream) {
    const float* x   = (const float*)d_in[0];   // [4,256,2048]
    const float* enc = (const float*)d_in[1];   // [4,2048,1024]
    const float* Wq  = (const float*)d_in[2];   // [2048,2048]
    const float* bq  = (const float*)d_in[3];
    const float* Wk  = (const float*)d_in[4];   // [1024,2048]
    const float* bk  = (const float*)d_in[5];
    const float* Wv  = (const float*)d_in[6];   // [1024,2048]
    const float* bv  = (const float*)d_in[7];
    const float* Wo  = (const float*)d_in[8];   // [2048,2048]
    const float* bo  = (const float*)d_in[9];
    float* out = (float*)d_out;                 // [4,256,2048] fp32

    // ws layout (MB offsets) with liveness overlays (same as R3):
    //   0: x_bf(4) | 4: enc_bf(16) | 20: WqT(8) | 28: WkvT(8) | 36: V_bf(32)
    //  68: K_bf(32) | 100: WoT(8) | 108: Q_bf(4) | 112: Vt(64)
    //  S_bf(64)@0 | Pq(16)@36 | Ppv(16.8)@68 | Po(16)@0 | ctx_bf(4)@108
    char* ws = (char*)d_ws;
    const size_t MB = 1024 * 1024;
    unsigned short* x_bf   = (unsigned short*)(ws + 0 * MB);
    unsigned short* enc_bf = (unsigned short*)(ws + 4 * MB);
    unsigned short* WqT    = (unsigned short*)(ws + 20 * MB);
    unsigned short* WkvT   = (unsigned short*)(ws + 28 * MB);
    unsigned short* V_bf   = (unsigned short*)(ws + 36 * MB);
    unsigned short* K_bf   = (unsigned short*)(ws + 68 * MB);
    unsigned short* WoT    = (unsigned short*)(ws + 100 * MB);
    unsigned short* Q_bf   = (unsigned short*)(ws + 108 * MB);
    unsigned short* Vt     = (unsigned short*)(ws + 112 * MB);
    unsigned short* S_bf   = (unsigned short*)(ws + 0 * MB);
    float*          Pq     = (float*)(ws + 36 * MB);
    float*          Ppv    = (float*)(ws + 68 * MB);
    float*          Po     = (float*)(ws + 0 * MB);
    unsigned short* ctx_bf = (unsigned short*)(ws + 108 * MB);

    dim3 tb(32, 8);

    // casts
    cast_f32_bf16<<<2048, 256, 0, stream>>>(x, x_bf, 2097152);
    cast_f32_bf16<<<8192, 256, 0, stream>>>(enc, enc_bf, 8388608);

    // weight transposes (fp32 [K,N] -> bf16 [N,K]); Wk/Wv stacked into WkvT [4096,1024]
    transpose_f32_bf16<<<dim3(64, 64), tb, 0, stream>>>(Wq, WqT, 2048, 2048);
    transpose_f32_bf16<<<dim3(64, 32), tb, 0, stream>>>(Wk, WkvT, 1024, 2048);
    transpose_f32_bf16<<<dim3(64, 32), tb, 0, stream>>>(Wv, WkvT + 2048 * 1024, 1024, 2048);
    transpose_f32_bf16<<<dim3(64, 64), tb, 0, stream>>>(Wo, WoT, 2048, 2048);

    // Q partials = x @ Wq, split-K=2 -> Pq[2][1024][2048]
    gemm_bt<4><<<dim3(16, 8, 2), 256, 0, stream>>>(x_bf, WqT, nullptr, nullptr, Pq, nullptr,
                                                   1024, 2048, 1024, 2048, 2048, 0, 0, 1, 0);
    combine_q_rope<<<4096, 256, 0, stream>>>(Pq, bq, Q_bf);

    // K|V = enc @ [Wk|Wv] + bias -> head layouts (fused, N=4096)
    gemm_bt<1><<<dim3(32, 64, 1), 256, 0, stream>>>(enc_bf, WkvT, bk, bv, K_bf, V_bf,
                                                    8192, 4096, 1024, 1024, 1024, 0, 0, 1, 2048);

    // V -> Vt [B,H,HD,LE]
    transpose_bf16_batched<<<dim3(4, 64, 64), tb, 0, stream>>>(V_bf, Vt, 2048, 128);

    // S = Q @ K^T (scale folded into Q) -> bf16 [64][256][2048]
    gemm_bt<2><<<dim3(16, 2, 64), 256, 0, stream>>>(Q_bf, K_bf, nullptr, nullptr, S_bf, nullptr,
                                                    256, 2048, 128, 128, 128,
                                                    256 * 128, 2048 * 128, 1, 0);
    softmax_rows<<<16384, 256, 0, stream>>>(S_bf);

    // ctx partials = P @ V, split-K=2: z = s*64+bh -> Ppv[2][64][256][128]
    gemm_bt<4><<<dim3(1, 2, 128), 256, 0, stream>>>(S_bf, Vt, nullptr, nullptr, Ppv, nullptr,
                                                    256, 128, 1024, 2048, 2048,
                                                    256 * 2048, 128 * 2048, 64, 0);
    combine_pv<<<2048, 256, 0, stream>>>(Ppv, ctx_bf);

    // O partials = ctx @ Wo, split-K=2 -> Po[2][1024][2048]
    gemm_bt<4><<<dim3(16, 8, 2), 256, 0, stream>>>(ctx_bf, WoT, nullptr, nullptr, Po, nullptr,
                                                   1024, 2048, 1024, 2048, 2048, 0, 0, 1, 0);
    combine_o<<<2048, 256, 0, stream>>>(Po, bo, out);
}

// Round 6
// 406.030 us; speedup vs baseline: 1.5007x; 1.5007x over previous
//
#include <hip/hip_runtime.h>

// CrossAttention: B=4, L=256, D=2048, LE=2048, DE=1024, H=16, HD=128
// R6 = R5 with two bugfixes:
//   (1) Ppv moved 36MB -> 68MB (was clobbering live S_bf during PV GEMM)
//   (2) Q-GEMM split-K=4 now K=512 per split (was 256: half the reduction)
// Pipeline: triple-buffered LDS K-loop, raw s_barrier + explicit
// s_waitcnt vmcnt(4); stage i+2 issued after barrier of iter i.

#define B_ 4
#define L_ 256
#define D_ 2048
#define LE_ 2048
#define DE_ 1024
#define H_ 16
#define HD_ 128

using f32x4  = __attribute__((ext_vector_type(4))) float;
using bf16x8 = __attribute__((ext_vector_type(8))) short;

__device__ __forceinline__ unsigned short f2bf(float f) {
    union { float f; unsigned int u; } v; v.f = f;
    unsigned int r = v.u + 0x7fffu + ((v.u >> 16) & 1u);   // RNE
    return (unsigned short)(r >> 16);
}
__device__ __forceinline__ float b2f(unsigned short h) {
    union { unsigned int u; float f; } v; v.u = ((unsigned int)h) << 16;
    return v.f;
}

__device__ __forceinline__ void load_lds16(const void* g, void* l) {
    __builtin_amdgcn_global_load_lds((const __attribute__((address_space(1))) void*)g,
                                     (__attribute__((address_space(3))) void*)l, 16, 0, 0);
}

// ---------------- elementwise cast fp32 -> bf16 (vec4) ----------------
__global__ void cast_f32_bf16(const float* __restrict__ in, unsigned short* __restrict__ out, int n) {
    int i = (blockIdx.x * 256 + threadIdx.x) * 4;
    if (i < n) {
        float4 v = *(const float4*)(in + i);
        ushort4 o;
        o.x = f2bf(v.x); o.y = f2bf(v.y); o.z = f2bf(v.z); o.w = f2bf(v.w);
        *(ushort4*)(out + i) = o;
    }
}

// ---------------- tiled transpose fp32[R,C] -> bf16[C,R] ----------------
__global__ void transpose_f32_bf16(const float* __restrict__ in, unsigned short* __restrict__ out,
                                   int R, int C) {
    __shared__ float t[32][33];
    int r0 = blockIdx.y * 32, c0 = blockIdx.x * 32;
    int tx = threadIdx.x, ty = threadIdx.y;            // block (32,8)
    #pragma unroll
    for (int i = 0; i < 32; i += 8) t[ty + i][tx] = in[(long)(r0 + ty + i) * C + c0 + tx];
    __syncthreads();
    #pragma unroll
    for (int i = 0; i < 32; i += 8) out[(long)(c0 + ty + i) * R + r0 + tx] = f2bf(t[tx][ty + i]);
}

// ---------------- tiled transpose bf16[R,C] -> bf16[C,R], batched (z) ----------------
__global__ void transpose_bf16_batched(const unsigned short* __restrict__ in,
                                       unsigned short* __restrict__ out, int R, int C) {
    __shared__ unsigned short t[32][33];
    long zo = (long)blockIdx.z * R * C;
    int r0 = blockIdx.y * 32, c0 = blockIdx.x * 32;
    int tx = threadIdx.x, ty = threadIdx.y;            // block (32,8)
    #pragma unroll
    for (int i = 0; i < 32; i += 8) t[ty + i][tx] = in[zo + (long)(r0 + ty + i) * C + c0 + tx];
    __syncthreads();
    #pragma unroll
    for (int i = 0; i < 32; i += 8) out[zo + (long)(c0 + ty + i) * R + r0 + tx] = t[tx][ty + i];
}

// ---------------- combine Q split-K=4 partials + bias + RoPE -> Q_bf head layout ----------------
// P: [4][1024][2048] fp32 (m = b*256+l, n = h*128+d). Q_bf: [(b*16+h)*256+l][128]
__global__ void combine_q_rope(const float* __restrict__ P, const float* __restrict__ bq,
                               unsigned short* __restrict__ Q) {
    int gid = blockIdx.x * 256 + threadIdx.x;          // 1,048,576 pairs
    int p = gid & 63;
    int h = (gid >> 6) & 15;
    int m = gid >> 10;                                 // 0..1023
    int n = h * 128 + 2 * p;
    long i0 = (long)m * 2048 + n;
    float q1 = bq[n], q2 = bq[n + 1];
    #pragma unroll
    for (int pt = 0; pt < 4; pt++) {
        float2 a = *(const float2*)(P + (long)pt * 2097152 + i0);
        q1 += a.x; q2 += a.y;
    }
    int l = m & 255, b = m >> 8;
    float inv = powf(10000.0f, -(float)p * (1.0f / 64.0f));
    float s, c;
    sincosf((float)l * inv, &s, &c);
    const float sc = 0.08838834764831845f;             // 1/sqrt(128)
    long qi = (((long)(b * 16 + h) * 256 + l) << 7) + 2 * p;
    ushort2 o;
    o.x = f2bf((q1 * c - q2 * s) * sc);
    o.y = f2bf((q1 * s + q2 * c) * sc);
    *(ushort2*)(Q + qi) = o;
}

// ---------------- combine PV split-K=4 partials -> ctx_bf ----------------
// P: [4][64][256][128] fp32. ctx_bf: [(b*256+m)*2048 + h*128 + d]
__global__ void combine_pv(const float* __restrict__ P, unsigned short* __restrict__ ctx) {
    int gid = blockIdx.x * 256 + threadIdx.x;          // 524288 threads, 4 floats each
    long e = (long)gid * 4;
    float4 a = *(const float4*)(P + e);
    #pragma unroll
    for (int pt = 1; pt < 4; pt++) {
        float4 b = *(const float4*)(P + (long)pt * 2097152 + e);
        a.x += b.x; a.y += b.y; a.z += b.z; a.w += b.w;
    }
    int bh = (int)(e >> 15);
    int m  = (int)((e >> 7) & 255);
    int d  = (int)(e & 127);
    int bb = bh >> 4, h = bh & 15;
    ushort4 o;
    o.x = f2bf(a.x); o.y = f2bf(a.y); o.z = f2bf(a.z); o.w = f2bf(a.w);
    *(ushort4*)(ctx + ((long)(bb * 256 + m)) * 2048 + h * 128 + d) = o;
}

// ---------------- combine O split-K=4 partials + bias -> fp32 out ----------------
__global__ void combine_o(const float* __restrict__ P, const float* __restrict__ bo,
                          float* __restrict__ out) {
    int gid = blockIdx.x * 256 + threadIdx.x;          // 524288
    long e = (long)gid * 4;
    int n = (int)(e & 2047);
    float4 r = *(const float4*)(bo + n);
    #pragma unroll
    for (int pt = 0; pt < 4; pt++) {
        float4 a = *(const float4*)(P + (long)pt * 2097152 + e);
        r.x += a.x; r.y += a.y; r.z += a.z; r.w += a.w;
    }
    *(float4*)(out + e) = r;
}

// ---------------- row softmax, in-place on bf16 rows of 2048 (16B/thread) ----------------
__launch_bounds__(256)
__global__ void softmax_rows(unsigned short* __restrict__ S) {
    long row = blockIdx.x;
    unsigned short* p = S + row * 2048;
    int t = threadIdx.x, w = t >> 6, lane = t & 63;
    bf16x8 raw = *(const bf16x8*)(p + t * 8);
    float v[8];
    float mx = -1e30f;
    #pragma unroll
    for (int i = 0; i < 8; i++) { v[i] = b2f((unsigned short)raw[i]); mx = fmaxf(mx, v[i]); }
    #pragma unroll
    for (int o = 32; o; o >>= 1) mx = fmaxf(mx, __shfl_xor(mx, o));
    __shared__ float redm[4], reds[4];
    if (lane == 0) redm[w] = mx;
    __syncthreads();
    mx = fmaxf(fmaxf(redm[0], redm[1]), fmaxf(redm[2], redm[3]));
    float sum = 0.f;
    #pragma unroll
    for (int i = 0; i < 8; i++) { v[i] = __expf(v[i] - mx); sum += v[i]; }
    #pragma unroll
    for (int o = 32; o; o >>= 1) sum += __shfl_xor(sum, o);
    if (lane == 0) reds[w] = sum;
    __syncthreads();
    sum = reds[0] + reds[1] + reds[2] + reds[3];
    float r = 1.0f / sum;
    bf16x8 res;
    #pragma unroll
    for (int i = 0; i < 8; i++) res[i] = (short)f2bf(v[i] * r);
    *(bf16x8*)(p + t * 8) = res;
}

// ---------------- bf16 GEMM: C[M,N] = A[M,K] * Bt[N,K]^T, batched / split-K ----------------
// Triple-buffered K-loop: stages i and i+1 in flight (4 loads/thread each).
// Per iter: s_waitcnt vmcnt(4) (drain ONLY stage i), raw s_barrier, issue
// stage i+2, compute stage i. Stage i+2 gets two compute phases of cover.
// EPI 1: bf16 KV head relayout; n<nsplit -> outA(K_bf)+biasA, else outB(V_bf)+biasB
// EPI 2: bf16 plain batched [z][M,N]
// EPI 4: fp32 split-K partial; z -> s=z/zdiv, bh=z%zdiv; out[(s*zdiv+bh)][M][N]
template <int EPI>
__launch_bounds__(256)
__global__ void gemm_bt(const unsigned short* __restrict__ A, const unsigned short* __restrict__ Bt,
                        const float* __restrict__ biasA, const float* __restrict__ biasB,
                        void* __restrict__ outA, void* __restrict__ outB,
                        int M, int N, int K, int lda, int ldb,
                        long strideA, long strideB, int zdiv, int nsplit) {
    __shared__ __align__(16) unsigned short smem[24576];  // 48 KB: 3 stages x (A 8KB + B 8KB)
    const int z = blockIdx.z;
    int s = 0, bh = z;
    if constexpr (EPI == 4) { s = z / zdiv; bh = z - s * zdiv; }
    const unsigned short* Ab = A + (long)bh * strideA + (long)s * K;
    const unsigned short* Bb = Bt + (long)bh * strideB + (long)s * K;
    const int m0 = blockIdx.y * 128, n0 = blockIdx.x * 128;
    const int tid = threadIdx.x;
    const int w = tid >> 6, lane = tid & 63;
    const int quad = lane >> 4, l16 = lane & 15;
    const int wr = w >> 1, wc = w & 1;
    const int srow = lane >> 2;          // staging: row within 16-row chunk
    const int scol = (lane & 3) * 8;     // staging: k-offset (elements)

    f32x4 acc[4][4] = {};

    auto stage = [&](int k0, int p) {    // 4 loads per thread (2 A-chunks + 2 B-chunks)
        unsigned short* As = smem + p * 8192;
        unsigned short* Bs = As + 4096;
        #pragma unroll
        for (int q = 0; q < 2; q++) {
            int ci = q * 4 + w;          // 1KB chunk id, 0..7
            int row = ci * 16 + srow;
            load_lds16(Ab + (long)(m0 + row) * lda + k0 + scol, (void*)(As + ci * 512));
            load_lds16(Bb + (long)(n0 + row) * ldb + k0 + scol, (void*)(Bs + ci * 512));
        }
    };

    const int nk = K >> 5;               // >= 4 for all our shapes
    stage(0, 0);
    stage(32, 1);
    int p = 0;                           // buffer index = i % 3
    for (int i = 0; i < nk; i++) {
        if (i + 1 < nk) asm volatile("s_waitcnt vmcnt(4)" ::: "memory");
        else            asm volatile("s_waitcnt vmcnt(0)" ::: "memory");
        __builtin_amdgcn_s_barrier();
        if (i + 2 < nk) {
            int pn = p + 2; if (pn >= 3) pn -= 3;
            stage((i + 2) << 5, pn);
        }
        const unsigned short* As = smem + p * 8192;
        const unsigned short* Bs = As + 4096;
        bf16x8 af[4], bfr[4];
        #pragma unroll
        for (int ii = 0; ii < 4; ii++) {
            int r = wr * 64 + ii * 16 + l16;
            af[ii] = *(const bf16x8*)(As + r * 32 + quad * 8);
        }
        #pragma unroll
        for (int j = 0; j < 4; j++) {
            int r = wc * 64 + j * 16 + l16;
            bfr[j] = *(const bf16x8*)(Bs + r * 32 + quad * 8);
        }
        #pragma unroll
        for (int ii = 0; ii < 4; ii++)
            #pragma unroll
            for (int j = 0; j < 4; j++)
                acc[ii][j] = __builtin_amdgcn_mfma_f32_16x16x32_bf16(af[ii], bfr[j], acc[ii][j], 0, 0, 0);
        if (++p >= 3) p -= 3;
    }
    __syncthreads();                     // all waves done with tiles; smem reused below

    // ---------------- epilogue via LDS bounce ----------------
    if constexpr (EPI == 1 || EPI == 2) {
        const bool second = (EPI == 1) && (n0 >= nsplit);
        const float* bias = second ? biasB : biasA;
        const int n0e = second ? n0 - nsplit : n0;
        unsigned short* dst = (unsigned short*)(second ? outB : outA);
        #pragma unroll
        for (int pp = 0; pp < 2; pp++) {
            if (wr == pp) {
                #pragma unroll
                for (int i = 0; i < 4; i++)
                    #pragma unroll
                    for (int j = 0; j < 4; j++)
                        #pragma unroll
                        for (int r = 0; r < 4; r++) {
                            int ml = i * 16 + quad * 4 + r;          // 0..63
                            int n  = wc * 64 + j * 16 + l16;         // 0..127
                            float v = acc[i][j][r];
                            if (bias) v += bias[n0e + n];
                            smem[ml * 136 + n] = f2bf(v);
                        }
            }
            __syncthreads();
            #pragma unroll
            for (int pass = 0; pass < 4; pass++) {
                int row = pass * 16 + (tid >> 4);                    // 0..63
                int seg = tid & 15;                                  // x8 elems
                bf16x8 val = *(const bf16x8*)(smem + row * 136 + seg * 8);
                int m = m0 + pp * 64 + row;
                if constexpr (EPI == 1) {
                    int h = n0e >> 7;                                // 0..15
                    int b = m >> 11, mrow = m & 2047;
                    long idx = (((long)(b * 16 + h)) << 11) + mrow;
                    *(bf16x8*)(dst + (idx << 7) + seg * 8) = val;
                } else {
                    *(bf16x8*)((unsigned short*)outA + (long)z * M * N + (long)m * N + n0 + seg * 8) = val;
                }
            }
            __syncthreads();
        }
    } else {
        // fp32 split-K partial
        float* smf = (float*)smem;
        long zo = ((long)s * zdiv + bh) * (long)M * N;
        #pragma unroll
        for (int q4 = 0; q4 < 4; q4++) {
            if (wr == (q4 >> 1)) {
                #pragma unroll
                for (int ii = 0; ii < 2; ii++) {
                    int i = (q4 & 1) * 2 + ii;
                    #pragma unroll
                    for (int j = 0; j < 4; j++)
                        #pragma unroll
                        for (int r = 0; r < 4; r++) {
                            int ml = ii * 16 + quad * 4 + r;         // 0..31
                            int n  = wc * 64 + j * 16 + l16;
                            smf[ml * 132 + n] = acc[i][j][r];
                        }
                }
            }
            __syncthreads();
            #pragma unroll
            for (int pass = 0; pass < 4; pass++) {
                int row = pass * 8 + (tid >> 5);                     // 0..31
                int seg = tid & 31;                                  // x4 floats
                float4 val = *(const float4*)(smf + row * 132 + seg * 4);
                int m = m0 + q4 * 32 + row;
                *(float4*)((float*)outA + zo + (long)m * N + n0 + seg * 4) = val;
            }
            __syncthreads();
        }
    }
}

extern "C" void kernel_launch(void* const* d_in, const int* in_sizes, int n_in,
                              void* d_out, int out_size, void* d_ws, size_t ws_size,
                              hipStream_t stream) {
    const float* x   = (const float*)d_in[0];   // [4,256,2048]
    const float* enc = (const float*)d_in[1];   // [4,2048,1024]
    const float* Wq  = (const float*)d_in[2];   // [2048,2048]
    const float* bq  = (const float*)d_in[3];
    const float* Wk  = (const float*)d_in[4];   // [1024,2048]
    const float* bk  = (const float*)d_in[5];
    const float* Wv  = (const float*)d_in[6];   // [1024,2048]
    const float* bv  = (const float*)d_in[7];
    const float* Wo  = (const float*)d_in[8];   // [2048,2048]
    const float* bo  = (const float*)d_in[9];
    float* out = (float*)d_out;                 // [4,256,2048] fp32

    // ws layout (MB offsets) with liveness overlays:
    //   0: x_bf(4) | 4: enc_bf(16) | 20: WqT(8) | 28: WkvT(8) | 36: V_bf(32)
    //  68: K_bf(32) | 100: WoT(8) | 108: Q_bf(4) | 112: Vt(64)
    //  Pq(32)@36  [x@Wq partials; written before KV fills V_bf; dead after combine_q]
    //  S_bf(64)@0 [x/enc/WqT/WkvT dead by S-GEMM]
    //  Ppv(32)@68 [K_bf dead after S-GEMM; 68..100, under WoT@100]  (R5 bug: was @36 under live S_bf)
    //  Po(32)@0   [S_bf dead after PV]
    //  ctx_bf(4)@108 [Q_bf dead after S-GEMM]
    char* ws = (char*)d_ws;
    const size_t MB = 1024 * 1024;
    unsigned short* x_bf   = (unsigned short*)(ws + 0 * MB);
    unsigned short* enc_bf = (unsigned short*)(ws + 4 * MB);
    unsigned short* WqT    = (unsigned short*)(ws + 20 * MB);
    unsigned short* WkvT   = (unsigned short*)(ws + 28 * MB);
    unsigned short* V_bf   = (unsigned short*)(ws + 36 * MB);
    unsigned short* K_bf   = (unsigned short*)(ws + 68 * MB);
    unsigned short* WoT    = (unsigned short*)(ws + 100 * MB);
    unsigned short* Q_bf   = (unsigned short*)(ws + 108 * MB);
    unsigned short* Vt     = (unsigned short*)(ws + 112 * MB);
    unsigned short* S_bf   = (unsigned short*)(ws + 0 * MB);
    float*          Pq     = (float*)(ws + 36 * MB);
    float*          Ppv    = (float*)(ws + 68 * MB);
    float*          Po     = (float*)(ws + 0 * MB);
    unsigned short* ctx_bf = (unsigned short*)(ws + 108 * MB);

    dim3 tb(32, 8);

    // casts
    cast_f32_bf16<<<2048, 256, 0, stream>>>(x, x_bf, 2097152);
    cast_f32_bf16<<<8192, 256, 0, stream>>>(enc, enc_bf, 8388608);

    // weight transposes (fp32 [K,N] -> bf16 [N,K]); Wk/Wv stacked into WkvT [4096,1024]
    transpose_f32_bf16<<<dim3(64, 64), tb, 0, stream>>>(Wq, WqT, 2048, 2048);
    transpose_f32_bf16<<<dim3(64, 32), tb, 0, stream>>>(Wk, WkvT, 1024, 2048);
    transpose_f32_bf16<<<dim3(64, 32), tb, 0, stream>>>(Wv, WkvT + 2048 * 1024, 1024, 2048);
    transpose_f32_bf16<<<dim3(64, 64), tb, 0, stream>>>(Wo, WoT, 2048, 2048);

    // Q partials = x @ Wq, split-K=4 (K=512 each) -> Pq[4][1024][2048]
    gemm_bt<4><<<dim3(16, 8, 4), 256, 0, stream>>>(x_bf, WqT, nullptr, nullptr, Pq, nullptr,
                                                   1024, 2048, 512, 2048, 2048, 0, 0, 1, 0);
    combine_q_rope<<<4096, 256, 0, stream>>>(Pq, bq, Q_bf);

    // K|V = enc @ [Wk|Wv] + bias -> head layouts (fused, N=4096)
    gemm_bt<1><<<dim3(32, 64, 1), 256, 0, stream>>>(enc_bf, WkvT, bk, bv, K_bf, V_bf,
                                                    8192, 4096, 1024, 1024, 1024, 0, 0, 1, 2048);

    // V -> Vt [B,H,HD,LE]
    transpose_bf16_batched<<<dim3(4, 64, 64), tb, 0, stream>>>(V_bf, Vt, 2048, 128);

    // S = Q @ K^T (scale folded into Q) -> bf16 [64][256][2048]
    gemm_bt<2><<<dim3(16, 2, 64), 256, 0, stream>>>(Q_bf, K_bf, nullptr, nullptr, S_bf, nullptr,
                                                    256, 2048, 128, 128, 128,
                                                    256 * 128, 2048 * 128, 1, 0);
    softmax_rows<<<16384, 256, 0, stream>>>(S_bf);

    // ctx partials = P @ V, split-K=4 (K=512 each): z = s*64+bh -> Ppv[4][64][256][128]
    gemm_bt<4><<<dim3(1, 2, 256), 256, 0, stream>>>(S_bf, Vt, nullptr, nullptr, Ppv, nullptr,
                                                    256, 128, 512, 2048, 2048,
                                                    256 * 2048, 128 * 2048, 64, 0);
    combine_pv<<<2048, 256, 0, stream>>>(Ppv, ctx_bf);

    // O partials = ctx @ Wo, split-K=4 (K=512 each) -> Po[4][1024][2048]
    gemm_bt<4><<<dim3(16, 8, 4), 256, 0, stream>>>(ctx_bf, WoT, nullptr, nullptr, Po, nullptr,
                                                   1024, 2048, 512, 2048, 2048, 0, 0, 1, 0);
    combine_o<<<2048, 256, 0, stream>>>(Po, bo, out);
}